// Round 12
// baseline (4931.353 us; speedup 1.0000x reference)
//
#include <hip/hip_runtime.h>
#include <math.h>

#define NB 256     // f32 fallback grid
#define NBK 512    // fp16 kernel grid: 2 blocks/CU
#define NT 1024
#define NW 16      // waves per block
#define TT 100
#define MM 10
#define NN 10
#define HID 2000
#define H1 1600
#define H2 400
#define G3 6000    // 3*HID
#define KP 2048    // padded K for fp16 weights
#define RPB 24     // rows per block-task

#define SCOPE_AGENT __HIP_MEMORY_SCOPE_AGENT

typedef _Float16 h2v __attribute__((ext_vector_type(2)));

__device__ __forceinline__ float sigf(float x) { return 1.f / (1.f + __expf(-x)); }
__device__ __forceinline__ float tanhfast(float x) { return 2.f / (1.f + __expf(-2.f * x)) - 1.f; }

// ---- cross-XCD coherent access (bypass non-coherent L2, no fences) ----
__device__ __forceinline__ void st_coh(float* p, float v) {
  __hip_atomic_store(p, v, __ATOMIC_RELAXED, SCOPE_AGENT);
}
__device__ __forceinline__ float2 ld_coh2(const float* p) {
  unsigned long long v = __hip_atomic_load((const unsigned long long*)p,
                                           __ATOMIC_RELAXED, SCOPE_AGENT);
  union { unsigned long long u; float2 f; } c; c.u = v; return c.f;
}
__device__ __forceinline__ unsigned ld_coh_u32(const unsigned* p) {
  return __hip_atomic_load(p, __ATOMIC_RELAXED, SCOPE_AGENT);
}
__device__ __forceinline__ void st_coh_u32(unsigned* p, unsigned v) {
  __hip_atomic_store(p, v, __ATOMIC_RELAXED, SCOPE_AGENT);
}
__device__ __forceinline__ void stage_coh(const float* __restrict__ src,
                                          float* __restrict__ dst, int n, int tid) {
  const int n2 = n >> 1;
  for (int j = tid; j < n2; j += NT) {
    float2 v = ld_coh2(src + 2 * j);
    dst[2 * j]     = v.x;
    dst[2 * j + 1] = v.y;
  }
}

// ---- f16-pair pack/unpack for comm buffers ----
__device__ __forceinline__ unsigned pack2(float a, float b) {
  union { unsigned u; h2v h; } c;
  c.h[0] = (_Float16)a; c.h[1] = (_Float16)b;
  return c.u;
}
__device__ __forceinline__ float2 upk(unsigned u) {
  union { unsigned u; h2v h; } c; c.u = u;
  float2 r; r.x = (float)c.h[0]; r.y = (float)c.h[1]; return r;
}

// ---- two-level grid barrier (validated rounds 5..11), nblk-parameterized ----
__device__ __forceinline__ void gridbar(unsigned* flags, unsigned* release,
                                        unsigned ep, int tid, int blk, int nblk) {
  __syncthreads();
  if (tid == 0)
    __hip_atomic_store(flags + blk * 16, ep, __ATOMIC_RELAXED, SCOPE_AGENT);
  if (blk == 0) {
    if (tid < nblk) {
      while (__hip_atomic_load(flags + tid * 16, __ATOMIC_RELAXED, SCOPE_AGENT) < ep)
        __builtin_amdgcn_s_sleep(1);
    }
    __syncthreads();
    if (tid == 0)
      __hip_atomic_store(release, ep, __ATOMIC_RELAXED, SCOPE_AGENT);
  } else {
    if (tid == 0) {
      while (__hip_atomic_load(release, __ATOMIC_RELAXED, SCOPE_AGENT) < ep)
        __builtin_amdgcn_s_sleep(1);
    }
  }
  __syncthreads();
}

// ---- point-to-point flags ----
__device__ __forceinline__ void set_flag(unsigned* f, unsigned v, int tid) {
  __syncthreads();   // drain this block's prior coherent stores
  if (tid == 0) __hip_atomic_store(f, v, __ATOMIC_RELAXED, SCOPE_AGENT);
}
__device__ __forceinline__ void wait_flag(const unsigned* f, unsigned v, int tid) {
  if (tid == 0) {
    while (__hip_atomic_load(f, __ATOMIC_RELAXED, SCOPE_AGENT) < v)
      __builtin_amdgcn_s_sleep(1);
  }
  __syncthreads();
}

// one row dot-product per wave (f32); fallback path
template<int K>
__device__ __forceinline__ float rowdotT(const float* __restrict__ row,
                                         const float* __restrict__ x, int ln) {
  constexpr int NFULL = K / 256;
  constexpr int REM   = K - NFULL * 256;
  const int base = ln * 4;
  float4 w[NFULL + (REM ? 1 : 0)];
  #pragma unroll
  for (int i = 0; i < NFULL; ++i)
    w[i] = *reinterpret_cast<const float4*>(row + base + i * 256);
  bool tail = false;
  if constexpr (REM != 0) {
    tail = (base + NFULL * 256 + 3 < K);
    if (tail) w[NFULL] = *reinterpret_cast<const float4*>(row + base + NFULL * 256);
  }
  float acc = 0.f;
  #pragma unroll
  for (int i = 0; i < NFULL; ++i) {
    const float4 xv = *reinterpret_cast<const float4*>(x + base + i * 256);
    acc = fmaf(w[i].x, xv.x, acc);
    acc = fmaf(w[i].y, xv.y, acc);
    acc = fmaf(w[i].z, xv.z, acc);
    acc = fmaf(w[i].w, xv.w, acc);
  }
  if constexpr (REM != 0) {
    if (tail) {
      const float4 xv = *reinterpret_cast<const float4*>(x + base + NFULL * 256);
      acc = fmaf(w[NFULL].x, xv.x, acc);
      acc = fmaf(w[NFULL].y, xv.y, acc);
      acc = fmaf(w[NFULL].z, xv.z, acc);
      acc = fmaf(w[NFULL].w, xv.w, acc);
    }
  }
  #pragma unroll
  for (int off = 32; off; off >>= 1) acc += __shfl_xor(acc, off, 64);
  return acc;
}

// ---- balanced 24-row fp16 block-task sweep (r6/r8-proven geometry) ----
// Output packed as f16 pairs into u32 comm buffer (outp may be null).
__device__ __forceinline__ void sweep24(const _Float16* __restrict__ W,
                                        const float* __restrict__ bias,
                                        int row0, int nrows,
                                        const _Float16* __restrict__ xh,
                                        unsigned* __restrict__ outp,
                                        bool relu,
                                        int wv, int ln, int tid, float* red,
                                        float* __restrict__ gloc)
{
  const _Float16* wp = W + (size_t)row0 * KP + wv * 3072 + ln * 8;
  uint4 w[6];
  #pragma unroll
  for (int c = 0; c < 6; ++c)
    w[c] = *reinterpret_cast<const uint4*>(wp + c * 512);
  float a0 = 0.f, a1 = 0.f;
  const int first = (3 * wv) >> 1;
  #pragma unroll
  for (int c = 0; c < 6; ++c) {
    const int flat = wv * 3072 + c * 512;
    const int sel  = (flat >> 11) - first;       // 0 or 1, lane-invariant
    const int col  = (flat & (KP - 1)) + ln * 8;
    const uint4 xv = *reinterpret_cast<const uint4*>(xh + col);
    union { uint4 u; h2v h[4]; } wu, xu;
    wu.u = w[c]; xu.u = xv;
    float acc = sel ? a1 : a0;
    #pragma unroll
    for (int q = 0; q < 4; ++q)
      acc = __builtin_amdgcn_fdot2(wu.h[q], xu.h[q], acc, false);
    if (sel) a1 = acc; else a0 = acc;
  }
  #pragma unroll
  for (int off = 32; off; off >>= 1) {
    a0 += __shfl_xor(a0, off, 64);
    a1 += __shfl_xor(a1, off, 64);
  }
  __syncthreads();
  if (ln == 0) { red[wv * 2] = a0; red[wv * 2 + 1] = a1; }
  __syncthreads();
  if (tid < nrows) {
    const int k = tid / 3, m = tid % 3;
    float v = (m == 0) ? red[4 * k]
            : (m == 1) ? red[4 * k + 1] + red[4 * k + 2]
                       : red[4 * k + 3];
    v += bias[row0 + tid];
    if (relu) v = fmaxf(v, 0.f);
    gloc[tid] = v;
  }
  __syncthreads();
  if (outp && tid < (nrows >> 1))
    st_coh_u32(outp + (row0 >> 1) + tid, pack2(gloc[2 * tid], gloc[2 * tid + 1]));
}

// ---- GRU combine from packed comm buffers into local h (f32 + f16 copies) ----
__device__ __forceinline__ void combine_gru(const unsigned* __restrict__ gip,
                                            const unsigned* __restrict__ ghp,
                                            float* __restrict__ hl,
                                            _Float16* __restrict__ hh, int tid) {
  for (int j = tid; j < HID / 2; j += NT) {
    float2 ir = upk(ld_coh_u32(gip + j)),        hr = upk(ld_coh_u32(ghp + j));
    float2 iz = upk(ld_coh_u32(gip + 1000 + j)), hz = upk(ld_coh_u32(ghp + 1000 + j));
    float2 in_ = upk(ld_coh_u32(gip + 2000 + j)), hn = upk(ld_coh_u32(ghp + 2000 + j));
    float r0 = sigf(ir.x + hr.x), r1 = sigf(ir.y + hr.y);
    float z0 = sigf(iz.x + hz.x), z1 = sigf(iz.y + hz.y);
    float n0 = tanhfast(in_.x + r0 * hn.x), n1 = tanhfast(in_.y + r1 * hn.y);
    float o0 = (1.f - z0) * n0 + z0 * hl[2 * j];
    float o1 = (1.f - z1) * n1 + z1 * hl[2 * j + 1];
    hl[2 * j] = o0; hl[2 * j + 1] = o1;
    hh[2 * j] = (_Float16)o0; hh[2 * j + 1] = (_Float16)o1;
  }
  __syncthreads();
}

// ---- f32 -> fp16 padded-layout conversions ----
__global__ __launch_bounds__(256)
void convh(const float* __restrict__ src, _Float16* __restrict__ dst,
           int rows, int K, int padrows) {
  const size_t total = (size_t)padrows * KP;
  for (size_t i = (size_t)blockIdx.x * blockDim.x + threadIdx.x; i < total;
       i += (size_t)gridDim.x * blockDim.x) {
    const int r = (int)(i >> 11), c = (int)(i & (KP - 1));
    float v = (r < rows && c < K) ? src[(size_t)r * K + c] : 0.f;
    dst[i] = (_Float16)v;
  }
}
__global__ __launch_bounds__(256)
void convw1(const float* __restrict__ src, _Float16* __restrict__ dst) {
  const int i = blockIdx.x * 256 + threadIdx.x;   // grid 256 -> 65536 elems
  const int r = i >> 5, c = i & 31;
  float v = (r < H1 && c < 30) ? src[r * 30 + c] : 0.f;
  dst[i] = (_Float16)v;
}

// ================= fp16 main kernel: 512 blocks (2/CU), 2 barriers/step =====
__global__ __launch_bounds__(NT, 8)
void knet_f16(const float* __restrict__ y, const float* __restrict__ m1x0,
              const float* __restrict__ F, const float* __restrict__ Hm,
              const float* __restrict__ h0,
              const float* __restrict__ W1, const float* __restrict__ b1,
              const float* __restrict__ Wi0, const float* __restrict__ Wh0,
              const float* __restrict__ bi0, const float* __restrict__ bh0,
              const float* __restrict__ Wi1, const float* __restrict__ Wh1,
              const float* __restrict__ bi1, const float* __restrict__ bh1,
              const float* __restrict__ W2, const float* __restrict__ b2,
              const float* __restrict__ W3, const float* __restrict__ b3,
              float* __restrict__ out, float* __restrict__ ws)
{
  const int blk = blockIdx.x, tid = threadIdx.x;
  const int wv = tid >> 6, ln = tid & 63;

  unsigned* gi0p = (unsigned*)ws;          // 3000 u32 (6000 f16)
  unsigned* gh0p = gi0p + 3000;            // 3000
  unsigned* gi1p = gi0p + 6000;            // 3000
  unsigned* gh1p = gi0p + 9000;            // 2 x 3000 (parity dbuf)
  float* vpart_ws  = ws + 15000;           // 17 x 100 f32
  unsigned* kinpack = (unsigned*)(ws + 16704);  // 16 u32
  unsigned* flags   = (unsigned*)(ws + 16720);  // 512 slots x 16 u32
  unsigned* release = flags + NBK * 16;
  unsigned* vflag   = release + 16;             // 17 slots x 16
  unsigned* kflag   = vflag + 17 * 16;          // 1 word

  const _Float16* whbase = (const _Float16*)((const char*)ws + 131072);
  const _Float16* Wi0h = whbase;
  const _Float16* Wh0h = whbase + (size_t)G3 * KP;
  const _Float16* Wi1h = whbase + (size_t)2 * G3 * KP;
  const _Float16* Wh1h = whbase + (size_t)3 * G3 * KP;
  const _Float16* W2h  = whbase + (size_t)4 * G3 * KP;                 // 408 rows
  const _Float16* W1h  = whbase + (size_t)4 * G3 * KP + (size_t)408 * KP;

  __shared__ __align__(16) _Float16 ah[KP];
  __shared__ __align__(16) _Float16 h1h[KP];
  __shared__ __align__(16) _Float16 h2h[KP];
  __shared__ __align__(16) float h1l[HID];
  __shared__ __align__(16) float h2l[HID];
  __shared__ __align__(16) float xs[1728];
  __shared__ __align__(16) _Float16 kin_h[32];
  __shared__ float red[32];
  __shared__ float gloc_s[RPB];
  __shared__ float post_s[MM], prevpost_s[MM], prevprior_s[MM], prior_s[MM];
  __shared__ float dy_s[NN], yprev_s[NN], tmp_s[MM];
  __shared__ float d1_s[NN], d3_s[MM], d4_s[MM];
  __shared__ float kin_s[32], nrm_s[3];
  __shared__ float v_s[MM * NN], np_s[MM];

  for (int j = tid; j < HID; j += NT) {
    float v1 = h0[j], v2 = h0[HID + j];
    h1l[j] = v1; h2l[j] = v2;
    h1h[j] = (_Float16)v1; h2h[j] = (_Float16)v2;
  }
  for (int j = HID + tid; j < KP; j += NT) { h1h[j] = (_Float16)0.f; h2h[j] = (_Float16)0.f; }
  for (int j = H1 + tid; j < KP; j += NT) ah[j] = (_Float16)0.f;
  __syncthreads();

  const bool isSerial = (blk == NBK - 1);

  unsigned ep = 0;

  for (int t = 0; t < TT; ++t) {
    unsigned* gh1wp = gh1p + (t & 1) * 3000;
    const unsigned* gh1rp = gh1p + ((t + 1) & 1) * 3000;

    // ================= region 1 =================
    if (isSerial) {
      if (t > 0) {
        if (tid < 17) {
          while (__hip_atomic_load(vflag + tid * 16, __ATOMIC_RELAXED, SCOPE_AGENT) < (unsigned)t)
            __builtin_amdgcn_s_sleep(1);
        }
        __syncthreads();
        stage_coh(vpart_ws, xs, 1700, tid);
        __syncthreads();
        if (tid < MM * NN) {
          float s = b3[tid];
          #pragma unroll
          for (int k = 0; k < 17; ++k) s += xs[k * 100 + tid];
          v_s[tid] = s;
        }
        __syncthreads();
        if (tid < MM) {
          float np = prior_s[tid];
          #pragma unroll
          for (int j = 0; j < NN; ++j) np = fmaf(v_s[tid * NN + j], dy_s[j], np);
          out[tid * TT + (t - 1)] = np;
          np_s[tid] = np;
        }
        __syncthreads();
        if (tid < MM) {
          prevpost_s[tid]  = post_s[tid];
          prevprior_s[tid] = prior_s[tid];
          post_s[tid]      = np_s[tid];
        }
        __syncthreads();
      } else {
        if (tid < MM) {
          post_s[tid]      = m1x0[tid];
          prevpost_s[tid]  = 0.f;
          prevprior_s[tid] = m1x0[tid];
          float tv = 0.f;
          for (int j = 0; j < MM; ++j) tv = fmaf(F[tid * MM + j], m1x0[j], tv);
          tmp_s[tid] = tv;
        }
        __syncthreads();
        if (tid < NN) {
          float yp = 0.f;
          for (int j = 0; j < MM; ++j) yp = fmaf(Hm[tid * MM + j], tmp_s[j], yp);
          yprev_s[tid] = yp;
        }
        __syncthreads();
      }
      // features for step t
      if (tid < MM) {
        float pr = 0.f;
        for (int j = 0; j < MM; ++j) pr = fmaf(F[tid * MM + j], post_s[j], pr);
        prior_s[tid] = pr;
      }
      __syncthreads();
      if (tid < NN) {
        float my = 0.f;
        for (int j = 0; j < MM; ++j) my = fmaf(Hm[tid * MM + j], prior_s[j], my);
        float yt = y[tid * TT + t];
        dy_s[tid] = yt - my;
        d1_s[tid] = yt - ((t == 0) ? yprev_s[tid] : y[tid * TT + (t - 1)]);
        d3_s[tid] = post_s[tid] - prevpost_s[tid];
        d4_s[tid] = post_s[tid] - prevprior_s[tid];
      }
      __syncthreads();
      if (tid == 0) {
        float n1 = 0.f, n3 = 0.f, n4 = 0.f;
        for (int j = 0; j < NN; ++j) n1 += d1_s[j] * d1_s[j];
        for (int j = 0; j < MM; ++j) { n3 += d3_s[j] * d3_s[j]; n4 += d4_s[j] * d4_s[j]; }
        nrm_s[0] = fmaxf(sqrtf(n1), 1e-12f);
        nrm_s[1] = fmaxf(sqrtf(n3), 1e-12f);
        nrm_s[2] = fmaxf(sqrtf(n4), 1e-12f);
      }
      __syncthreads();
      if (tid < NN) kin_s[tid] = d1_s[tid] / nrm_s[0];
      if (tid < MM) {
        kin_s[NN + tid]      = d3_s[tid] / nrm_s[1];
        kin_s[NN + MM + tid] = d4_s[tid] / nrm_s[2];
      }
      __syncthreads();
      if (tid < 32) kin_h[tid] = (_Float16)((tid < 30) ? kin_s[tid] : 0.f);
      __syncthreads();
      if (tid < 16) st_coh_u32(kinpack + tid, ((const unsigned*)kin_h)[tid]);
      set_flag(kflag, (unsigned)(t + 1), tid);   // kin(t) published
    } else if (blk < 250) {
      // Wh0 stream (independent), then kin-wait -> local a -> Wi0
      sweep24(Wh0h, bh0, RPB * blk, RPB, h1h, gh0p, false, wv, ln, tid, red, gloc_s);
      wait_flag(kflag, (unsigned)(t + 1), tid);
      if (tid < 16) ((unsigned*)kin_h)[tid] = ld_coh_u32(kinpack + tid);
      __syncthreads();
      if (tid < 800) {   // a = relu(W1h @ kin), 2 rows/thread, local
        const _Float16* wp = W1h + (size_t)tid * 64;
        uint4 q[8];
        #pragma unroll
        for (int c = 0; c < 8; ++c)
          q[c] = *reinterpret_cast<const uint4*>(wp + c * 8);
        const uint4* kq = reinterpret_cast<const uint4*>(kin_h);
        union U { uint4 u; h2v h[4]; };
        U kk[4];
        #pragma unroll
        for (int c = 0; c < 4; ++c) kk[c].u = kq[c];
        const int r0 = 2 * tid;
        float s0 = b1[r0], s1 = b1[r0 + 1];
        #pragma unroll
        for (int c = 0; c < 4; ++c) {
          U qq; qq.u = q[c];
          #pragma unroll
          for (int p = 0; p < 4; ++p)
            s0 = __builtin_amdgcn_fdot2(qq.h[p], kk[c].h[p], s0, false);
        }
        #pragma unroll
        for (int c = 0; c < 4; ++c) {
          U qq; qq.u = q[c + 4];
          #pragma unroll
          for (int p = 0; p < 4; ++p)
            s1 = __builtin_amdgcn_fdot2(qq.h[p], kk[c].h[p], s1, false);
        }
        ah[r0]     = (_Float16)fmaxf(s0, 0.f);
        ah[r0 + 1] = (_Float16)fmaxf(s1, 0.f);
      }
      __syncthreads();
      sweep24(Wi0h, bi0, RPB * blk, RPB, ah, gi0p, false, wv, ln, tid, red, gloc_s);
    } else {
      // blocks 250..510: combine2 then Wh1 (250..499) or W2 (500..510)
      if (t > 0) combine_gru(gi1p, gh1rp, h2l, h2h, tid);
      if (blk < 500) {
        sweep24(Wh1h, bh1, RPB * (blk - 250), RPB, h2h, gh1wp, false, wv, ln, tid, red, gloc_s);
      } else if (t > 0) {
        #pragma unroll
        for (int rep = 0; rep < 2; ++rep) {
          const int task = (rep == 0) ? (blk - 500) : (blk - 489);
          if (task < 17) {
            const int row0 = RPB * task;
            const int nr = (H2 - row0 < RPB) ? (H2 - row0) : RPB;
            sweep24(W2h, b2, row0, nr, h2h, nullptr, true, wv, ln, tid, red, gloc_s);
            __syncthreads();
            if (tid < MM * NN) {
              float s = 0.f;
              const float* w3c = W3 + (size_t)tid * H2 + row0;
              for (int j = 0; j < nr; ++j) s = fmaf(w3c[j], gloc_s[j], s);
              st_coh(vpart_ws + task * 100 + tid, s);
            }
            set_flag(vflag + task * 16, (unsigned)t, tid);
          }
        }
      }
    }
    ++ep; gridbar(flags, release, ep, tid, blk, NBK);   // B1

    // ================= region 2: combine1 ; Wi1 =================
    if (!isSerial && blk < 500) {
      combine_gru(gi0p, gh0p, h1l, h1h, tid);
      if (blk >= 250)
        sweep24(Wi1h, bi1, RPB * (blk - 250), RPB, h1h, gi1p, false, wv, ln, tid, red, gloc_s);
    }
    ++ep; gridbar(flags, release, ep, tid, blk, NBK);   // B2
  }

  // ================= epilogue: combine2(T-1), W2, vpart, finalize =============
  if (blk >= 500 && blk < NBK - 1) {
    const unsigned* gh1fp = gh1p + ((TT + 1) & 1) * 3000;
    combine_gru(gi1p, gh1fp, h2l, h2h, tid);
    #pragma unroll
    for (int rep = 0; rep < 2; ++rep) {
      const int task = (rep == 0) ? (blk - 500) : (blk - 489);
      if (task < 17) {
        const int row0 = RPB * task;
        const int nr = (H2 - row0 < RPB) ? (H2 - row0) : RPB;
        sweep24(W2h, b2, row0, nr, h2h, nullptr, true, wv, ln, tid, red, gloc_s);
        __syncthreads();
        if (tid < MM * NN) {
          float s = 0.f;
          const float* w3c = W3 + (size_t)tid * H2 + row0;
          for (int j = 0; j < nr; ++j) s = fmaf(w3c[j], gloc_s[j], s);
          st_coh(vpart_ws + task * 100 + tid, s);
        }
        set_flag(vflag + task * 16, (unsigned)TT, tid);
      }
    }
  }
  if (isSerial) {
    if (tid < 17) {
      while (__hip_atomic_load(vflag + tid * 16, __ATOMIC_RELAXED, SCOPE_AGENT) < (unsigned)TT)
        __builtin_amdgcn_s_sleep(1);
    }
    __syncthreads();
    stage_coh(vpart_ws, xs, 1700, tid);
    __syncthreads();
    if (tid < MM * NN) {
      float s = b3[tid];
      #pragma unroll
      for (int k = 0; k < 17; ++k) s += xs[k * 100 + tid];
      v_s[tid] = s;
    }
    __syncthreads();
    if (tid < MM) {
      float np = prior_s[tid];
      #pragma unroll
      for (int j = 0; j < NN; ++j) np = fmaf(v_s[tid * NN + j], dy_s[j], np);
      out[tid * TT + (TT - 1)] = np;
    }
  }
}

// ================= f32 fallback (round-5 kernel, proven; 256 blocks) ==========
__global__ __launch_bounds__(NT)
void knet_f32(const float* __restrict__ y, const float* __restrict__ m1x0,
              const float* __restrict__ F, const float* __restrict__ Hm,
              const float* __restrict__ h0,
              const float* __restrict__ W1, const float* __restrict__ b1,
              const float* __restrict__ Wi0, const float* __restrict__ Wh0,
              const float* __restrict__ bi0, const float* __restrict__ bh0,
              const float* __restrict__ Wi1, const float* __restrict__ Wh1,
              const float* __restrict__ bi1, const float* __restrict__ bh1,
              const float* __restrict__ W2, const float* __restrict__ b2,
              const float* __restrict__ W3, const float* __restrict__ b3,
              float* __restrict__ out, float* __restrict__ ws)
{
  const int blk = blockIdx.x, tid = threadIdx.x;
  const int wv = tid >> 6, ln = tid & 63;

  float* a_ws   = ws;
  float* gi0_ws = ws + 1600;
  float* gh0_ws = ws + 7600;
  float* gi1_ws = ws + 13600;
  float* gh1_ws = ws + 19600;
  float* g_ws   = ws + 25600;
  unsigned* flags   = (unsigned*)(ws + 26624);
  unsigned* release = flags + NB * 16;

  __shared__ __align__(16) float xs[1664];
  __shared__ __align__(16) float h1l[HID];
  __shared__ __align__(16) float h2l[HID];
  __shared__ float post_s[MM], prevpost_s[MM], prevprior_s[MM], prior_s[MM];
  __shared__ float dy_s[NN], yprev_s[NN], tmp_s[MM];
  __shared__ float d1_s[NN], d3_s[MM], d4_s[MM];
  __shared__ float kin_s[32], nrm_s[3];
  __shared__ float v_s[MM * NN], np_s[MM];

  for (int j = tid; j < HID; j += NT) { h1l[j] = h0[j]; h2l[j] = h0[HID + j]; }
  __syncthreads();

  unsigned ep = 0;

  for (int t = 0; t < TT; ++t) {
    if (blk == NB - 1) {
      if (t > 0) {
        stage_coh(g_ws, xs, H2, tid);
        __syncthreads();
        for (int r = wv; r < MM * NN; r += NW) {
          float acc = rowdotT<H2>(W3 + (size_t)r * H2, xs, ln);
          if (ln == 0) v_s[r] = acc + b3[r];
        }
        __syncthreads();
        if (tid < MM) {
          float np = prior_s[tid];
          #pragma unroll
          for (int j = 0; j < NN; ++j) np = fmaf(v_s[tid * NN + j], dy_s[j], np);
          out[tid * TT + (t - 1)] = np;
          np_s[tid] = np;
        }
        __syncthreads();
        if (tid < MM) {
          prevpost_s[tid]  = post_s[tid];
          prevprior_s[tid] = prior_s[tid];
          post_s[tid]      = np_s[tid];
        }
        __syncthreads();
      } else {
        if (tid < MM) {
          post_s[tid]      = m1x0[tid];
          prevpost_s[tid]  = 0.f;
          prevprior_s[tid] = m1x0[tid];
          float tv = 0.f;
          for (int j = 0; j < MM; ++j) tv = fmaf(F[tid * MM + j], m1x0[j], tv);
          tmp_s[tid] = tv;
        }
        __syncthreads();
        if (tid < NN) {
          float yp = 0.f;
          for (int j = 0; j < MM; ++j) yp = fmaf(Hm[tid * MM + j], tmp_s[j], yp);
          yprev_s[tid] = yp;
        }
        __syncthreads();
      }
      if (tid < MM) {
        float pr = 0.f;
        for (int j = 0; j < MM; ++j) pr = fmaf(F[tid * MM + j], post_s[j], pr);
        prior_s[tid] = pr;
      }
      __syncthreads();
      if (tid < NN) {
        float my = 0.f;
        for (int j = 0; j < MM; ++j) my = fmaf(Hm[tid * MM + j], prior_s[j], my);
        float yt = y[tid * TT + t];
        dy_s[tid] = yt - my;
        d1_s[tid] = yt - ((t == 0) ? yprev_s[tid] : y[tid * TT + (t - 1)]);
        d3_s[tid] = post_s[tid] - prevpost_s[tid];
        d4_s[tid] = post_s[tid] - prevprior_s[tid];
      }
      __syncthreads();
      if (tid == 0) {
        float n1 = 0.f, n3 = 0.f, n4 = 0.f;
        for (int j = 0; j < NN; ++j) n1 += d1_s[j] * d1_s[j];
        for (int j = 0; j < MM; ++j) { n3 += d3_s[j] * d3_s[j]; n4 += d4_s[j] * d4_s[j]; }
        nrm_s[0] = fmaxf(sqrtf(n1), 1e-12f);
        nrm_s[1] = fmaxf(sqrtf(n3), 1e-12f);
        nrm_s[2] = fmaxf(sqrtf(n4), 1e-12f);
      }
      __syncthreads();
      if (tid < NN) kin_s[tid] = d1_s[tid] / nrm_s[0];
      if (tid < MM) {
        kin_s[NN + tid]      = d3_s[tid] / nrm_s[1];
        kin_s[NN + MM + tid] = d4_s[tid] / nrm_s[2];
      }
      __syncthreads();
      for (int r = tid; r < H1; r += NT) {
        float acc = b1[r];
        const float* row = W1 + (size_t)r * 30;
        #pragma unroll
        for (int k = 0; k < 30; ++k) acc = fmaf(row[k], kin_s[k], acc);
        st_coh(a_ws + r, fmaxf(acc, 0.f));
      }
    } else {
      const int gw = blk * NW + wv;
      for (int r = gw; r < G3; r += (NB - 1) * NW) {
        float acc = rowdotT<HID>(Wh1 + (size_t)r * HID, h2l, ln);
        if (ln == 0) st_coh(gh1_ws + r, acc + bh1[r]);
      }
      if (t == 0) {
        for (int r = gw; r < G3; r += (NB - 1) * NW) {
          float acc = rowdotT<HID>(Wh0 + (size_t)r * HID, h1l, ln);
          if (ln == 0) st_coh(gh0_ws + r, acc + bh0[r]);
        }
      }
    }
    ++ep; gridbar(flags, release, ep, tid, blk, NB);

    stage_coh(a_ws, xs, H1, tid);
    __syncthreads();
    {
      const int gw = blk * NW + wv;
      for (int r = gw; r < G3; r += NB * NW) {
        float acc = rowdotT<H1>(Wi0 + (size_t)r * H1, xs, ln);
        if (ln == 0) st_coh(gi0_ws + r, acc + bi0[r]);
      }
    }
    ++ep; gridbar(flags, release, ep, tid, blk, NB);

    {
      for (int j = tid; j < HID / 2; j += NT) {
        float2 ir = ld_coh2(gi0_ws + 2 * j),            hr = ld_coh2(gh0_ws + 2 * j);
        float2 iz = ld_coh2(gi0_ws + HID + 2 * j),      hz = ld_coh2(gh0_ws + HID + 2 * j);
        float2 in_ = ld_coh2(gi0_ws + 2 * HID + 2 * j), hn = ld_coh2(gh0_ws + 2 * HID + 2 * j);
        float r0 = sigf(ir.x + hr.x), r1 = sigf(ir.y + hr.y);
        float z0 = sigf(iz.x + hz.x), z1 = sigf(iz.y + hz.y);
        float n0 = tanhfast(in_.x + r0 * hn.x), n1 = tanhfast(in_.y + r1 * hn.y);
        h1l[2 * j]     = (1.f - z0) * n0 + z0 * h1l[2 * j];
        h1l[2 * j + 1] = (1.f - z1) * n1 + z1 * h1l[2 * j + 1];
      }
      __syncthreads();
      const int gw = blk * NW + wv;
      for (int r = gw; r < G3; r += NB * NW) {
        float acc = rowdotT<HID>(Wi1 + (size_t)r * HID, h1l, ln);
        if (ln == 0) st_coh(gi1_ws + r, acc + bi1[r]);
      }
    }
    ++ep; gridbar(flags, release, ep, tid, blk, NB);

    {
      for (int j = tid; j < HID / 2; j += NT) {
        float2 ir = ld_coh2(gi1_ws + 2 * j),            hr = ld_coh2(gh1_ws + 2 * j);
        float2 iz = ld_coh2(gi1_ws + HID + 2 * j),      hz = ld_coh2(gh1_ws + HID + 2 * j);
        float2 in_ = ld_coh2(gi1_ws + 2 * HID + 2 * j), hn = ld_coh2(gh1_ws + 2 * HID + 2 * j);
        float r0 = sigf(ir.x + hr.x), r1 = sigf(ir.y + hr.y);
        float z0 = sigf(iz.x + hz.x), z1 = sigf(iz.y + hz.y);
        float n0 = tanhfast(in_.x + r0 * hn.x), n1 = tanhfast(in_.y + r1 * hn.y);
        h2l[2 * j]     = (1.f - z0) * n0 + z0 * h2l[2 * j];
        h2l[2 * j + 1] = (1.f - z1) * n1 + z1 * h2l[2 * j + 1];
      }
      __syncthreads();
      const int gw = blk * NW + wv;
      for (int r = gw; r < H2 + G3; r += NB * NW) {
        if (r < H2) {
          float acc = rowdotT<HID>(W2 + (size_t)r * HID, h2l, ln);
          if (ln == 0) st_coh(g_ws + r, fmaxf(acc + b2[r], 0.f));
        } else {
          const int rr = r - H2;
          float acc = rowdotT<HID>(Wh0 + (size_t)rr * HID, h1l, ln);
          if (ln == 0) st_coh(gh0_ws + rr, acc + bh0[rr]);
        }
      }
    }
    ++ep; gridbar(flags, release, ep, tid, blk, NB);
  }

  if (blk == NB - 1) {
    stage_coh(g_ws, xs, H2, tid);
    __syncthreads();
    for (int r = wv; r < MM * NN; r += NW) {
      float acc = rowdotT<H2>(W3 + (size_t)r * H2, xs, ln);
      if (ln == 0) v_s[r] = acc + b3[r];
    }
    __syncthreads();
    if (tid < MM) {
      float np = prior_s[tid];
      #pragma unroll
      for (int j = 0; j < NN; ++j) np = fmaf(v_s[tid * NN + j], dy_s[j], np);
      out[tid * TT + (TT - 1)] = np;
    }
  }
}

extern "C" void kernel_launch(void* const* d_in, const int* in_sizes, int n_in,
                              void* d_out, int out_size, void* d_ws, size_t ws_size,
                              hipStream_t stream) {
  const float* y    = (const float*)d_in[0];
  const float* m1x0 = (const float*)d_in[1];
  const float* F    = (const float*)d_in[2];
  const float* Hm   = (const float*)d_in[3];
  const float* h0   = (const float*)d_in[4];
  const float* W1   = (const float*)d_in[5];
  const float* b1   = (const float*)d_in[6];
  const float* Wi0  = (const float*)d_in[7];
  const float* Wh0  = (const float*)d_in[8];
  const float* bi0  = (const float*)d_in[9];
  const float* bh0  = (const float*)d_in[10];
  const float* Wi1  = (const float*)d_in[11];
  const float* Wh1  = (const float*)d_in[12];
  const float* bi1  = (const float*)d_in[13];
  const float* bh1  = (const float*)d_in[14];
  const float* W2   = (const float*)d_in[15];
  const float* b2   = (const float*)d_in[16];
  const float* W3   = (const float*)d_in[17];
  const float* b3   = (const float*)d_in[18];
  float* out = (float*)d_out;
  float* ws  = (float*)d_ws;

  const size_t WBASE = 131072;
  const size_t NEED = WBASE +
      ((size_t)4 * G3 * KP + (size_t)408 * KP + (size_t)65536) * 2;

  void* args[] = { &y, &m1x0, &F, &Hm, &h0, &W1, &b1, &Wi0, &Wh0, &bi0, &bh0,
                   &Wi1, &Wh1, &bi1, &bh1, &W2, &b2, &W3, &b3, &out, &ws };

  int occ = 0;
  hipOccupancyMaxActiveBlocksPerMultiprocessor(&occ, (const void*)knet_f16, NT, 0);

  if (ws_size >= NEED && occ >= 2) {
    // zero flags region: flags(512) + release + vflag(17) + kflag, 16-u32 slots
    hipMemsetAsync((char*)d_ws + 16720 * 4, 0, (25216 - 16720) * 4, stream);
    _Float16* wh = (_Float16*)((char*)d_ws + WBASE);
    convh<<<2048, 256, 0, stream>>>(Wi0, wh,                         G3, H1,  G3);
    convh<<<2048, 256, 0, stream>>>(Wh0, wh + (size_t)G3 * KP,       G3, HID, G3);
    convh<<<2048, 256, 0, stream>>>(Wi1, wh + (size_t)2 * G3 * KP,   G3, HID, G3);
    convh<<<2048, 256, 0, stream>>>(Wh1, wh + (size_t)3 * G3 * KP,   G3, HID, G3);
    convh<<<2048, 256, 0, stream>>>(W2,  wh + (size_t)4 * G3 * KP,   H2, HID, 408);
    convw1<<<256, 256, 0, stream>>>(W1,  wh + (size_t)4 * G3 * KP + (size_t)408 * KP);
    hipLaunchCooperativeKernel((const void*)knet_f16, dim3(NBK), dim3(NT),
                               args, 0, stream);
  } else {
    hipMemsetAsync((char*)d_ws + 26624 * sizeof(float), 0, NB * 64 + 64, stream);
    hipLaunchCooperativeKernel((const void*)knet_f32, dim3(NB), dim3(NT),
                               args, 0, stream);
  }
}

// Round 13
// 3696.339 us; speedup vs baseline: 1.3341x; 1.3341x over previous
//
#include <hip/hip_runtime.h>
#include <math.h>

#define NB 256
#define NT 1024
#define NW 16      // waves per block
#define TT 100
#define MM 10
#define NN 10
#define HID 2000
#define H1 1600
#define H2 400
#define G3 6000    // 3*HID
#define KP 2048    // padded K for fp16 weights
#define RPB 24     // rows per block-task

#define SCOPE_AGENT __HIP_MEMORY_SCOPE_AGENT

typedef _Float16 h2v __attribute__((ext_vector_type(2)));

__device__ __forceinline__ float sigf(float x) { return 1.f / (1.f + __expf(-x)); }
__device__ __forceinline__ float tanhfast(float x) { return 2.f / (1.f + __expf(-2.f * x)) - 1.f; }

// ---- cross-XCD coherent access (bypass non-coherent L2, no fences) ----
__device__ __forceinline__ float ld_coh(const float* p) {
  return __hip_atomic_load(p, __ATOMIC_RELAXED, SCOPE_AGENT);
}
__device__ __forceinline__ void st_coh(float* p, float v) {
  __hip_atomic_store(p, v, __ATOMIC_RELAXED, SCOPE_AGENT);
}
__device__ __forceinline__ float2 ld_coh2(const float* p) {
  unsigned long long v = __hip_atomic_load((const unsigned long long*)p,
                                           __ATOMIC_RELAXED, SCOPE_AGENT);
  union { unsigned long long u; float2 f; } c; c.u = v; return c.f;
}
__device__ __forceinline__ void stage_coh(const float* __restrict__ src,
                                          float* __restrict__ dst, int n, int tid) {
  const int n2 = n >> 1;
  for (int j = tid; j < n2; j += NT) {
    float2 v = ld_coh2(src + 2 * j);
    dst[2 * j]     = v.x;
    dst[2 * j + 1] = v.y;
  }
}

// ---- two-level grid barrier (validated rounds 5..10) ----
__device__ __forceinline__ void gridbar(unsigned* flags, unsigned* release,
                                        unsigned ep, int tid, int blk) {
  __syncthreads();
  if (tid == 0)
    __hip_atomic_store(flags + blk * 16, ep, __ATOMIC_RELAXED, SCOPE_AGENT);
  if (blk == 0) {
    if (tid < NB) {
      while (__hip_atomic_load(flags + tid * 16, __ATOMIC_RELAXED, SCOPE_AGENT) < ep)
        __builtin_amdgcn_s_sleep(1);
    }
    __syncthreads();
    if (tid == 0)
      __hip_atomic_store(release, ep, __ATOMIC_RELAXED, SCOPE_AGENT);
  } else {
    if (tid == 0) {
      while (__hip_atomic_load(release, __ATOMIC_RELAXED, SCOPE_AGENT) < ep)
        __builtin_amdgcn_s_sleep(1);
    }
  }
  __syncthreads();
}

// ---- point-to-point flags (same coherence discipline as gridbar) ----
__device__ __forceinline__ void set_flag(unsigned* f, unsigned v, int tid) {
  __syncthreads();   // drain this block's prior coherent stores (vmcnt 0)
  if (tid == 0) __hip_atomic_store(f, v, __ATOMIC_RELAXED, SCOPE_AGENT);
}
__device__ __forceinline__ void wait_flag(const unsigned* f, unsigned v, int tid) {
  if (tid == 0) {
    while (__hip_atomic_load(f, __ATOMIC_RELAXED, SCOPE_AGENT) < v)
      __builtin_amdgcn_s_sleep(1);
  }
  __syncthreads();
}

// one row dot-product per wave (f32); x in LDS; K compile-time (fallback path)
template<int K>
__device__ __forceinline__ float rowdotT(const float* __restrict__ row,
                                         const float* __restrict__ x, int ln) {
  constexpr int NFULL = K / 256;
  constexpr int REM   = K - NFULL * 256;
  const int base = ln * 4;
  float4 w[NFULL + (REM ? 1 : 0)];
  #pragma unroll
  for (int i = 0; i < NFULL; ++i)
    w[i] = *reinterpret_cast<const float4*>(row + base + i * 256);
  bool tail = false;
  if constexpr (REM != 0) {
    tail = (base + NFULL * 256 + 3 < K);
    if (tail) w[NFULL] = *reinterpret_cast<const float4*>(row + base + NFULL * 256);
  }
  float acc = 0.f;
  #pragma unroll
  for (int i = 0; i < NFULL; ++i) {
    const float4 xv = *reinterpret_cast<const float4*>(x + base + i * 256);
    acc = fmaf(w[i].x, xv.x, acc);
    acc = fmaf(w[i].y, xv.y, acc);
    acc = fmaf(w[i].z, xv.z, acc);
    acc = fmaf(w[i].w, xv.w, acc);
  }
  if constexpr (REM != 0) {
    if (tail) {
      const float4 xv = *reinterpret_cast<const float4*>(x + base + NFULL * 256);
      acc = fmaf(w[NFULL].x, xv.x, acc);
      acc = fmaf(w[NFULL].y, xv.y, acc);
      acc = fmaf(w[NFULL].z, xv.z, acc);
      acc = fmaf(w[NFULL].w, xv.w, acc);
    }
  }
  #pragma unroll
  for (int off = 32; off; off >>= 1) acc += __shfl_xor(acc, off, 64);
  return acc;
}

// ---- balanced 24-row fp16 block-task sweep (monolithic, r6/r8-proven) ----
__device__ __forceinline__ void sweep24(const _Float16* __restrict__ W,
                                        const float* __restrict__ bias,
                                        int row0, int nrows,
                                        const _Float16* __restrict__ xh,
                                        float* __restrict__ outw,
                                        bool relu,
                                        int wv, int ln, int tid, float* red,
                                        float* __restrict__ gloc)
{
  const _Float16* wp = W + (size_t)row0 * KP + wv * 3072 + ln * 8;
  uint4 w[6];
  #pragma unroll
  for (int c = 0; c < 6; ++c)
    w[c] = *reinterpret_cast<const uint4*>(wp + c * 512);
  float a0 = 0.f, a1 = 0.f;
  const int first = (3 * wv) >> 1;
  #pragma unroll
  for (int c = 0; c < 6; ++c) {
    const int flat = wv * 3072 + c * 512;
    const int sel  = (flat >> 11) - first;       // 0 or 1, lane-invariant
    const int col  = (flat & (KP - 1)) + ln * 8;
    const uint4 xv = *reinterpret_cast<const uint4*>(xh + col);
    union { uint4 u; h2v h[4]; } wu, xu;
    wu.u = w[c]; xu.u = xv;
    float acc = sel ? a1 : a0;
    #pragma unroll
    for (int q = 0; q < 4; ++q)
      acc = __builtin_amdgcn_fdot2(wu.h[q], xu.h[q], acc, false);
    if (sel) a1 = acc; else a0 = acc;
  }
  #pragma unroll
  for (int off = 32; off; off >>= 1) {
    a0 += __shfl_xor(a0, off, 64);
    a1 += __shfl_xor(a1, off, 64);
  }
  __syncthreads();                 // protect red across back-to-back calls
  if (ln == 0) { red[wv * 2] = a0; red[wv * 2 + 1] = a1; }
  __syncthreads();
  if (tid < nrows) {
    const int k = tid / 3, m = tid % 3;
    float v = (m == 0) ? red[4 * k]
            : (m == 1) ? red[4 * k + 1] + red[4 * k + 2]
                       : red[4 * k + 3];
    v += bias[row0 + tid];
    if (relu) v = fmaxf(v, 0.f);
    if (gloc) gloc[tid] = v;
    if (outw) st_coh(outw + row0 + tid, v);
  }
}

// ---- f32 -> fp16 padded-layout conversions ----
__global__ __launch_bounds__(256)
void convh(const float* __restrict__ src, _Float16* __restrict__ dst,
           int rows, int K, int padrows) {
  const size_t total = (size_t)padrows * KP;
  for (size_t i = (size_t)blockIdx.x * blockDim.x + threadIdx.x; i < total;
       i += (size_t)gridDim.x * blockDim.x) {
    const int r = (int)(i >> 11), c = (int)(i & (KP - 1));
    float v = (r < rows && c < K) ? src[(size_t)r * K + c] : 0.f;
    dst[i] = (_Float16)v;
  }
}
__global__ __launch_bounds__(256)
void convw1(const float* __restrict__ src, _Float16* __restrict__ dst) {
  const int i = blockIdx.x * 256 + threadIdx.x;   // grid 256 -> 65536 elems
  const int r = i >> 5, c = i & 31;
  float v = (r < H1 && c < 30) ? src[r * 30 + c] : 0.f;
  dst[i] = (_Float16)v;
}

// ================= fp16 main kernel: merged-region, 2 barriers/step ==========
__global__ __launch_bounds__(NT)
void knet_f16(const float* __restrict__ y, const float* __restrict__ m1x0,
              const float* __restrict__ F, const float* __restrict__ Hm,
              const float* __restrict__ h0,
              const float* __restrict__ W1, const float* __restrict__ b1,
              const float* __restrict__ Wi0, const float* __restrict__ Wh0,
              const float* __restrict__ bi0, const float* __restrict__ bh0,
              const float* __restrict__ Wi1, const float* __restrict__ Wh1,
              const float* __restrict__ bi1, const float* __restrict__ bh1,
              const float* __restrict__ W2, const float* __restrict__ b2,
              const float* __restrict__ W3, const float* __restrict__ b3,
              float* __restrict__ out, float* __restrict__ ws)
{
  const int blk = blockIdx.x, tid = threadIdx.x;
  const int wv = tid >> 6, ln = tid & 63;

  float* a_ws     = ws;            // 1600 (unused in f16 path, kept for layout)
  float* gi0_ws   = ws + 1600;     // 6000
  float* gh0_ws   = ws + 7600;     // 6000
  float* gi1_ws   = ws + 13600;    // 6000
  float* gh1b     = ws + 19600;    // 2 x 6000 (double-buffered by step parity)
  float* g_ws     = ws + 31600;    // 400 (unused)
  float* vpart_ws = ws + 32000;    // 17 x 100
  unsigned* flags   = (unsigned*)(ws + 33728);   // 256 arrival slots x 64B
  unsigned* release = flags + 256 * 16;          // 1 release word
  unsigned* vflag   = release + 16;              // 17 slots x 64B
  unsigned* aflag   = vflag + 17 * 16;           // 1 word (kin flag)
  unsigned* kinpack = aflag + 16;                // 16 u32

  const _Float16* whbase = (const _Float16*)((const char*)ws + 152576);
  const _Float16* Wi0h = whbase;
  const _Float16* Wh0h = whbase + (size_t)G3 * KP;
  const _Float16* Wi1h = whbase + (size_t)2 * G3 * KP;
  const _Float16* Wh1h = whbase + (size_t)3 * G3 * KP;
  const _Float16* W2h  = whbase + (size_t)4 * G3 * KP;
  const _Float16* W1h  = whbase + (size_t)4 * G3 * KP + (size_t)408 * KP;

  __shared__ __align__(16) _Float16 ah[KP];
  __shared__ __align__(16) _Float16 h1h[KP];
  __shared__ __align__(16) _Float16 h2h[KP];
  __shared__ __align__(16) float h1l[HID];
  __shared__ __align__(16) float h2l[HID];
  __shared__ __align__(16) float xs[1728];
  __shared__ __align__(16) _Float16 kin_h[32];
  __shared__ float red[32];
  __shared__ float gloc_s[RPB];
  __shared__ float post_s[MM], prevpost_s[MM], prevprior_s[MM], prior_s[MM];
  __shared__ float dy_s[NN], yprev_s[NN], tmp_s[MM];
  __shared__ float d1_s[NN], d3_s[MM], d4_s[MM];
  __shared__ float kin_s[32], nrm_s[3];
  __shared__ float v_s[MM * NN], np_s[MM];

  for (int j = tid; j < HID; j += NT) {
    float v1 = h0[j], v2 = h0[HID + j];
    h1l[j] = v1; h2l[j] = v2;
    h1h[j] = (_Float16)v1; h2h[j] = (_Float16)v2;
  }
  for (int j = HID + tid; j < KP; j += NT) { h1h[j] = (_Float16)0.f; h2h[j] = (_Float16)0.f; }
  for (int j = H1 + tid; j < KP; j += NT) ah[j] = (_Float16)0.f;
  __syncthreads();

  unsigned ep = 0;

  for (int t = 0; t < TT; ++t) {
    float* gh1w = gh1b + (t & 1) * G3;           // written this region (gh1(t))
    float* gh1r = gh1b + ((t + 1) & 1) * G3;     // read by combine2 (gh1(t-1))

    // ======== region 1: [combine2, W2+vpart | Wh0] ; Wh1 ; kin-wait ; a ; Wi0 ====
    if (blk == NB - 1) {
      // ---- serial block: finalize(t-1), features(t), publish kin(t) ----
      if (t > 0) {
        if (tid < 17) {   // wait for the 17 W2-blocks' vpart
          while (__hip_atomic_load(vflag + tid * 16, __ATOMIC_RELAXED, SCOPE_AGENT) < (unsigned)t)
            __builtin_amdgcn_s_sleep(1);
        }
        __syncthreads();
        stage_coh(vpart_ws, xs, 1700, tid);
        __syncthreads();
        if (tid < MM * NN) {
          float s = b3[tid];
          #pragma unroll
          for (int k = 0; k < 17; ++k) s += xs[k * 100 + tid];
          v_s[tid] = s;
        }
        __syncthreads();
        if (tid < MM) {
          float np = prior_s[tid];
          #pragma unroll
          for (int j = 0; j < NN; ++j) np = fmaf(v_s[tid * NN + j], dy_s[j], np);
          out[tid * TT + (t - 1)] = np;
          np_s[tid] = np;
        }
        __syncthreads();
        if (tid < MM) {
          prevpost_s[tid]  = post_s[tid];
          prevprior_s[tid] = prior_s[tid];
          post_s[tid]      = np_s[tid];
        }
        __syncthreads();
      } else {
        if (tid < MM) {
          post_s[tid]      = m1x0[tid];
          prevpost_s[tid]  = 0.f;
          prevprior_s[tid] = m1x0[tid];
          float tv = 0.f;
          for (int j = 0; j < MM; ++j) tv = fmaf(F[tid * MM + j], m1x0[j], tv);
          tmp_s[tid] = tv;
        }
        __syncthreads();
        if (tid < NN) {
          float yp = 0.f;
          for (int j = 0; j < MM; ++j) yp = fmaf(Hm[tid * MM + j], tmp_s[j], yp);
          yprev_s[tid] = yp;
        }
        __syncthreads();
      }
      // features for step t
      if (tid < MM) {
        float pr = 0.f;
        for (int j = 0; j < MM; ++j) pr = fmaf(F[tid * MM + j], post_s[j], pr);
        prior_s[tid] = pr;
      }
      __syncthreads();
      if (tid < NN) {
        float my = 0.f;
        for (int j = 0; j < MM; ++j) my = fmaf(Hm[tid * MM + j], prior_s[j], my);
        float yt = y[tid * TT + t];
        dy_s[tid] = yt - my;
        d1_s[tid] = yt - ((t == 0) ? yprev_s[tid] : y[tid * TT + (t - 1)]);
        d3_s[tid] = post_s[tid] - prevpost_s[tid];
        d4_s[tid] = post_s[tid] - prevprior_s[tid];
      }
      __syncthreads();
      if (tid == 0) {
        float n1 = 0.f, n3 = 0.f, n4 = 0.f;
        for (int j = 0; j < NN; ++j) n1 += d1_s[j] * d1_s[j];
        for (int j = 0; j < MM; ++j) { n3 += d3_s[j] * d3_s[j]; n4 += d4_s[j] * d4_s[j]; }
        nrm_s[0] = fmaxf(sqrtf(n1), 1e-12f);
        nrm_s[1] = fmaxf(sqrtf(n3), 1e-12f);
        nrm_s[2] = fmaxf(sqrtf(n4), 1e-12f);
      }
      __syncthreads();
      if (tid < NN) kin_s[tid] = d1_s[tid] / nrm_s[0];
      if (tid < MM) {
        kin_s[NN + tid]      = d3_s[tid] / nrm_s[1];
        kin_s[NN + MM + tid] = d4_s[tid] / nrm_s[2];
      }
      __syncthreads();
      if (tid < 32) kin_h[tid] = (_Float16)((tid < 30) ? kin_s[tid] : 0.f);
      __syncthreads();
      if (tid < 800) {   // a = relu(W1h @ kin), 2 rows/thread -> a_ws
        const _Float16* wp = W1h + (size_t)tid * 64;
        uint4 q[8];
        #pragma unroll
        for (int c = 0; c < 8; ++c)
          q[c] = *reinterpret_cast<const uint4*>(wp + c * 8);
        const uint4* kq = reinterpret_cast<const uint4*>(kin_h);
        union { uint4 u; h2v h[4]; } kk[4], qq;
        #pragma unroll
        for (int c = 0; c < 4; ++c) kk[c].u = kq[c];
        const int r0 = 2 * tid;
        float s0 = b1[r0], s1 = b1[r0 + 1];
        #pragma unroll
        for (int c = 0; c < 4; ++c) {
          qq.u = q[c];
          #pragma unroll
          for (int p = 0; p < 4; ++p)
            s0 = __builtin_amdgcn_fdot2(qq.h[p], kk[c].h[p], s0, false);
        }
        #pragma unroll
        for (int c = 0; c < 4; ++c) {
          qq.u = q[c + 4];
          #pragma unroll
          for (int p = 0; p < 4; ++p)
            s1 = __builtin_amdgcn_fdot2(qq.h[p], kk[c].h[p], s1, false);
        }
        st_coh(a_ws + r0,     fmaxf(s0, 0.f));
        st_coh(a_ws + r0 + 1, fmaxf(s1, 0.f));
      }
      set_flag(aflag, (unsigned)(t + 1), tid);   // a(t) ready
    } else {
      // ---- worker blocks ----
      if (blk >= 17) {
        // Wh0 tasks first (independent of combine2): gh0(t) = Wh0 @ h1n(t-1)
        if (blk <= 249) {
          sweep24(Wh0h, bh0, RPB * (blk - 17), RPB, h1h, gh0_ws, false, wv, ln, tid, red, nullptr);
        } else {
          #pragma unroll
          for (int i = 0; i < 4; ++i) {
            const int task = 233 + (blk - 250) + 5 * i;
            if (task < 250)
              sweep24(Wh0h, bh0, RPB * task, RPB, h1h, gh0_ws, false, wv, ln, tid, red, nullptr);
          }
        }
      }
      if (t > 0) {
        // combine2 -> h2n(t-1) (reads gi1(t-1), gh1r; all protected by B2(t-1))
        for (int j = tid; j < HID / 2; j += NT) {
          float2 ir = ld_coh2(gi1_ws + 2 * j),            hr = ld_coh2(gh1r + 2 * j);
          float2 iz = ld_coh2(gi1_ws + HID + 2 * j),      hz = ld_coh2(gh1r + HID + 2 * j);
          float2 in_ = ld_coh2(gi1_ws + 2 * HID + 2 * j), hn = ld_coh2(gh1r + 2 * HID + 2 * j);
          float r0 = sigf(ir.x + hr.x), r1 = sigf(ir.y + hr.y);
          float z0 = sigf(iz.x + hz.x), z1 = sigf(iz.y + hz.y);
          float n0 = tanhfast(in_.x + r0 * hn.x), n1 = tanhfast(in_.y + r1 * hn.y);
          float o0 = (1.f - z0) * n0 + z0 * h2l[2 * j];
          float o1 = (1.f - z1) * n1 + z1 * h2l[2 * j + 1];
          h2l[2 * j] = o0; h2l[2 * j + 1] = o1;
          h2h[2 * j] = (_Float16)o0; h2h[2 * j + 1] = (_Float16)o1;
        }
        __syncthreads();
        if (blk < 17) {
          // W2 task + W3 partials + vpart flag (gates the serial block)
          const int row0 = RPB * blk;
          const int nr = (H2 - row0 < RPB) ? (H2 - row0) : RPB;
          sweep24(W2h, b2, row0, nr, h2h, nullptr, true, wv, ln, tid, red, gloc_s);
          __syncthreads();
          if (tid < MM * NN) {
            float s = 0.f;
            const float* w3c = W3 + (size_t)tid * H2 + row0;
            for (int j = 0; j < nr; ++j) s = fmaf(w3c[j], gloc_s[j], s);
            st_coh(vpart_ws + blk * 100 + tid, s);
          }
          set_flag(vflag + blk * 16, (unsigned)t, tid);
        }
      }
      // Wh1 task: gh1(t) = Wh1 @ h2n(t-1)
      if (blk <= 249)
        sweep24(Wh1h, bh1, RPB * blk, RPB, h2h, gh1w, false, wv, ln, tid, red, nullptr);
      // wait for a(t), then Wi0
      if (blk <= 249) {
        wait_flag(aflag, (unsigned)(t + 1), tid);
        const int n2 = H1 >> 1;
        for (int j = tid; j < n2; j += NT) {
          float2 v = ld_coh2(a_ws + 2 * j);
          ah[2 * j]     = (_Float16)v.x;
          ah[2 * j + 1] = (_Float16)v.y;
        }
        __syncthreads();
        sweep24(Wi0h, bi0, RPB * blk, RPB, ah, gi0_ws, false, wv, ln, tid, red, nullptr);
      }
    }
    ++ep; gridbar(flags, release, ep, tid, blk);   // B1: gi0 + gh0 complete

    // ======== region 2: combine1 -> h1n(t); Wi1 ========
    if (blk != NB - 1) {
      for (int j = tid; j < HID / 2; j += NT) {
        float2 ir = ld_coh2(gi0_ws + 2 * j),            hr = ld_coh2(gh0_ws + 2 * j);
        float2 iz = ld_coh2(gi0_ws + HID + 2 * j),      hz = ld_coh2(gh0_ws + HID + 2 * j);
        float2 in_ = ld_coh2(gi0_ws + 2 * HID + 2 * j), hn = ld_coh2(gh0_ws + 2 * HID + 2 * j);
        float r0 = sigf(ir.x + hr.x), r1 = sigf(ir.y + hr.y);
        float z0 = sigf(iz.x + hz.x), z1 = sigf(iz.y + hz.y);
        float n0 = tanhfast(in_.x + r0 * hn.x), n1 = tanhfast(in_.y + r1 * hn.y);
        float o0 = (1.f - z0) * n0 + z0 * h1l[2 * j];
        float o1 = (1.f - z1) * n1 + z1 * h1l[2 * j + 1];
        h1l[2 * j] = o0; h1l[2 * j + 1] = o1;
        h1h[2 * j] = (_Float16)o0; h1h[2 * j + 1] = (_Float16)o1;
      }
      __syncthreads();
      if (blk <= 249)
        sweep24(Wi1h, bi1, RPB * blk, RPB, h1h, gi1_ws, false, wv, ln, tid, red, nullptr);
    }
    ++ep; gridbar(flags, release, ep, tid, blk);   // B2: gi1 + gh1(t) complete
  }

  // ======== epilogue: combine2(T-1), W2, vpart, finalize(T-1) ========
  if (blk < 17) {
    float* gh1r = gh1b + ((TT + 1) & 1) * G3;     // gh1(TT-1)
    for (int j = tid; j < HID / 2; j += NT) {
      float2 ir = ld_coh2(gi1_ws + 2 * j),            hr = ld_coh2(gh1r + 2 * j);
      float2 iz = ld_coh2(gi1_ws + HID + 2 * j),      hz = ld_coh2(gh1r + HID + 2 * j);
      float2 in_ = ld_coh2(gi1_ws + 2 * HID + 2 * j), hn = ld_coh2(gh1r + 2 * HID + 2 * j);
      float r0 = sigf(ir.x + hr.x), r1 = sigf(ir.y + hr.y);
      float z0 = sigf(iz.x + hz.x), z1 = sigf(iz.y + hz.y);
      float n0 = tanhfast(in_.x + r0 * hn.x), n1 = tanhfast(in_.y + r1 * hn.y);
      float o0 = (1.f - z0) * n0 + z0 * h2l[2 * j];
      float o1 = (1.f - z1) * n1 + z1 * h2l[2 * j + 1];
      h2h[2 * j] = (_Float16)o0; h2h[2 * j + 1] = (_Float16)o1;
    }
    __syncthreads();
    const int row0 = RPB * blk;
    const int nr = (H2 - row0 < RPB) ? (H2 - row0) : RPB;
    sweep24(W2h, b2, row0, nr, h2h, nullptr, true, wv, ln, tid, red, gloc_s);
    __syncthreads();
    if (tid < MM * NN) {
      float s = 0.f;
      const float* w3c = W3 + (size_t)tid * H2 + row0;
      for (int j = 0; j < nr; ++j) s = fmaf(w3c[j], gloc_s[j], s);
      st_coh(vpart_ws + blk * 100 + tid, s);
    }
    set_flag(vflag + blk * 16, (unsigned)TT, tid);
  }
  if (blk == NB - 1) {
    if (tid < 17) {
      while (__hip_atomic_load(vflag + tid * 16, __ATOMIC_RELAXED, SCOPE_AGENT) < (unsigned)TT)
        __builtin_amdgcn_s_sleep(1);
    }
    __syncthreads();
    stage_coh(vpart_ws, xs, 1700, tid);
    __syncthreads();
    if (tid < MM * NN) {
      float s = b3[tid];
      #pragma unroll
      for (int k = 0; k < 17; ++k) s += xs[k * 100 + tid];
      v_s[tid] = s;
    }
    __syncthreads();
    if (tid < MM) {
      float np = prior_s[tid];
      #pragma unroll
      for (int j = 0; j < NN; ++j) np = fmaf(v_s[tid * NN + j], dy_s[j], np);
      out[tid * TT + (TT - 1)] = np;
    }
  }
}

// ================= f32 fallback (round-5 kernel, proven; own layout) ==========
__global__ __launch_bounds__(NT)
void knet_f32(const float* __restrict__ y, const float* __restrict__ m1x0,
              const float* __restrict__ F, const float* __restrict__ Hm,
              const float* __restrict__ h0,
              const float* __restrict__ W1, const float* __restrict__ b1,
              const float* __restrict__ Wi0, const float* __restrict__ Wh0,
              const float* __restrict__ bi0, const float* __restrict__ bh0,
              const float* __restrict__ Wi1, const float* __restrict__ Wh1,
              const float* __restrict__ bi1, const float* __restrict__ bh1,
              const float* __restrict__ W2, const float* __restrict__ b2,
              const float* __restrict__ W3, const float* __restrict__ b3,
              float* __restrict__ out, float* __restrict__ ws)
{
  const int blk = blockIdx.x, tid = threadIdx.x;
  const int wv = tid >> 6, ln = tid & 63;

  float* a_ws   = ws;
  float* gi0_ws = ws + 1600;
  float* gh0_ws = ws + 7600;
  float* gi1_ws = ws + 13600;
  float* gh1_ws = ws + 19600;
  float* g_ws   = ws + 25600;
  unsigned* flags   = (unsigned*)(ws + 26624);
  unsigned* release = flags + NB * 16;

  __shared__ __align__(16) float xs[1664];
  __shared__ __align__(16) float h1l[HID];
  __shared__ __align__(16) float h2l[HID];
  __shared__ float post_s[MM], prevpost_s[MM], prevprior_s[MM], prior_s[MM];
  __shared__ float dy_s[NN], yprev_s[NN], tmp_s[MM];
  __shared__ float d1_s[NN], d3_s[MM], d4_s[MM];
  __shared__ float kin_s[32], nrm_s[3];
  __shared__ float v_s[MM * NN], np_s[MM];

  for (int j = tid; j < HID; j += NT) { h1l[j] = h0[j]; h2l[j] = h0[HID + j]; }
  __syncthreads();

  unsigned ep = 0;

  for (int t = 0; t < TT; ++t) {
    if (blk == NB - 1) {
      if (t > 0) {
        stage_coh(g_ws, xs, H2, tid);
        __syncthreads();
        for (int r = wv; r < MM * NN; r += NW) {
          float acc = rowdotT<H2>(W3 + (size_t)r * H2, xs, ln);
          if (ln == 0) v_s[r] = acc + b3[r];
        }
        __syncthreads();
        if (tid < MM) {
          float np = prior_s[tid];
          #pragma unroll
          for (int j = 0; j < NN; ++j) np = fmaf(v_s[tid * NN + j], dy_s[j], np);
          out[tid * TT + (t - 1)] = np;
          np_s[tid] = np;
        }
        __syncthreads();
        if (tid < MM) {
          prevpost_s[tid]  = post_s[tid];
          prevprior_s[tid] = prior_s[tid];
          post_s[tid]      = np_s[tid];
        }
        __syncthreads();
      } else {
        if (tid < MM) {
          post_s[tid]      = m1x0[tid];
          prevpost_s[tid]  = 0.f;
          prevprior_s[tid] = m1x0[tid];
          float tv = 0.f;
          for (int j = 0; j < MM; ++j) tv = fmaf(F[tid * MM + j], m1x0[j], tv);
          tmp_s[tid] = tv;
        }
        __syncthreads();
        if (tid < NN) {
          float yp = 0.f;
          for (int j = 0; j < MM; ++j) yp = fmaf(Hm[tid * MM + j], tmp_s[j], yp);
          yprev_s[tid] = yp;
        }
        __syncthreads();
      }
      if (tid < MM) {
        float pr = 0.f;
        for (int j = 0; j < MM; ++j) pr = fmaf(F[tid * MM + j], post_s[j], pr);
        prior_s[tid] = pr;
      }
      __syncthreads();
      if (tid < NN) {
        float my = 0.f;
        for (int j = 0; j < MM; ++j) my = fmaf(Hm[tid * MM + j], prior_s[j], my);
        float yt = y[tid * TT + t];
        dy_s[tid] = yt - my;
        d1_s[tid] = yt - ((t == 0) ? yprev_s[tid] : y[tid * TT + (t - 1)]);
        d3_s[tid] = post_s[tid] - prevpost_s[tid];
        d4_s[tid] = post_s[tid] - prevprior_s[tid];
      }
      __syncthreads();
      if (tid == 0) {
        float n1 = 0.f, n3 = 0.f, n4 = 0.f;
        for (int j = 0; j < NN; ++j) n1 += d1_s[j] * d1_s[j];
        for (int j = 0; j < MM; ++j) { n3 += d3_s[j] * d3_s[j]; n4 += d4_s[j] * d4_s[j]; }
        nrm_s[0] = fmaxf(sqrtf(n1), 1e-12f);
        nrm_s[1] = fmaxf(sqrtf(n3), 1e-12f);
        nrm_s[2] = fmaxf(sqrtf(n4), 1e-12f);
      }
      __syncthreads();
      if (tid < NN) kin_s[tid] = d1_s[tid] / nrm_s[0];
      if (tid < MM) {
        kin_s[NN + tid]      = d3_s[tid] / nrm_s[1];
        kin_s[NN + MM + tid] = d4_s[tid] / nrm_s[2];
      }
      __syncthreads();
      for (int r = tid; r < H1; r += NT) {
        float acc = b1[r];
        const float* row = W1 + (size_t)r * 30;
        #pragma unroll
        for (int k = 0; k < 30; ++k) acc = fmaf(row[k], kin_s[k], acc);
        st_coh(a_ws + r, fmaxf(acc, 0.f));
      }
    } else {
      const int gw = blk * NW + wv;
      for (int r = gw; r < G3; r += (NB - 1) * NW) {
        float acc = rowdotT<HID>(Wh1 + (size_t)r * HID, h2l, ln);
        if (ln == 0) st_coh(gh1_ws + r, acc + bh1[r]);
      }
      if (t == 0) {
        for (int r = gw; r < G3; r += (NB - 1) * NW) {
          float acc = rowdotT<HID>(Wh0 + (size_t)r * HID, h1l, ln);
          if (ln == 0) st_coh(gh0_ws + r, acc + bh0[r]);
        }
      }
    }
    ++ep; gridbar(flags, release, ep, tid, blk);

    stage_coh(a_ws, xs, H1, tid);
    __syncthreads();
    {
      const int gw = blk * NW + wv;
      for (int r = gw; r < G3; r += NB * NW) {
        float acc = rowdotT<H1>(Wi0 + (size_t)r * H1, xs, ln);
        if (ln == 0) st_coh(gi0_ws + r, acc + bi0[r]);
      }
    }
    ++ep; gridbar(flags, release, ep, tid, blk);

    {
      for (int j = tid; j < HID / 2; j += NT) {
        float2 ir = ld_coh2(gi0_ws + 2 * j),            hr = ld_coh2(gh0_ws + 2 * j);
        float2 iz = ld_coh2(gi0_ws + HID + 2 * j),      hz = ld_coh2(gh0_ws + HID + 2 * j);
        float2 in_ = ld_coh2(gi0_ws + 2 * HID + 2 * j), hn = ld_coh2(gh0_ws + 2 * HID + 2 * j);
        float r0 = sigf(ir.x + hr.x), r1 = sigf(ir.y + hr.y);
        float z0 = sigf(iz.x + hz.x), z1 = sigf(iz.y + hz.y);
        float n0 = tanhfast(in_.x + r0 * hn.x), n1 = tanhfast(in_.y + r1 * hn.y);
        h1l[2 * j]     = (1.f - z0) * n0 + z0 * h1l[2 * j];
        h1l[2 * j + 1] = (1.f - z1) * n1 + z1 * h1l[2 * j + 1];
      }
      __syncthreads();
      const int gw = blk * NW + wv;
      for (int r = gw; r < G3; r += NB * NW) {
        float acc = rowdotT<HID>(Wi1 + (size_t)r * HID, h1l, ln);
        if (ln == 0) st_coh(gi1_ws + r, acc + bi1[r]);
      }
    }
    ++ep; gridbar(flags, release, ep, tid, blk);

    {
      for (int j = tid; j < HID / 2; j += NT) {
        float2 ir = ld_coh2(gi1_ws + 2 * j),            hr = ld_coh2(gh1_ws + 2 * j);
        float2 iz = ld_coh2(gi1_ws + HID + 2 * j),      hz = ld_coh2(gh1_ws + HID + 2 * j);
        float2 in_ = ld_coh2(gi1_ws + 2 * HID + 2 * j), hn = ld_coh2(gh1_ws + 2 * HID + 2 * j);
        float r0 = sigf(ir.x + hr.x), r1 = sigf(ir.y + hr.y);
        float z0 = sigf(iz.x + hz.x), z1 = sigf(iz.y + hz.y);
        float n0 = tanhfast(in_.x + r0 * hn.x), n1 = tanhfast(in_.y + r1 * hn.y);
        h2l[2 * j]     = (1.f - z0) * n0 + z0 * h2l[2 * j];
        h2l[2 * j + 1] = (1.f - z1) * n1 + z1 * h2l[2 * j + 1];
      }
      __syncthreads();
      const int gw = blk * NW + wv;
      for (int r = gw; r < H2 + G3; r += NB * NW) {
        if (r < H2) {
          float acc = rowdotT<HID>(W2 + (size_t)r * HID, h2l, ln);
          if (ln == 0) st_coh(g_ws + r, fmaxf(acc + b2[r], 0.f));
        } else {
          const int rr = r - H2;
          float acc = rowdotT<HID>(Wh0 + (size_t)rr * HID, h1l, ln);
          if (ln == 0) st_coh(gh0_ws + rr, acc + bh0[rr]);
        }
      }
    }
    ++ep; gridbar(flags, release, ep, tid, blk);
  }

  if (blk == NB - 1) {
    stage_coh(g_ws, xs, H2, tid);
    __syncthreads();
    for (int r = wv; r < MM * NN; r += NW) {
      float acc = rowdotT<H2>(W3 + (size_t)r * H2, xs, ln);
      if (ln == 0) v_s[r] = acc + b3[r];
    }
    __syncthreads();
    if (tid < MM) {
      float np = prior_s[tid];
      #pragma unroll
      for (int j = 0; j < NN; ++j) np = fmaf(v_s[tid * NN + j], dy_s[j], np);
      out[tid * TT + (TT - 1)] = np;
    }
  }
}

extern "C" void kernel_launch(void* const* d_in, const int* in_sizes, int n_in,
                              void* d_out, int out_size, void* d_ws, size_t ws_size,
                              hipStream_t stream) {
  const float* y    = (const float*)d_in[0];
  const float* m1x0 = (const float*)d_in[1];
  const float* F    = (const float*)d_in[2];
  const float* Hm   = (const float*)d_in[3];
  const float* h0   = (const float*)d_in[4];
  const float* W1   = (const float*)d_in[5];
  const float* b1   = (const float*)d_in[6];
  const float* Wi0  = (const float*)d_in[7];
  const float* Wh0  = (const float*)d_in[8];
  const float* bi0  = (const float*)d_in[9];
  const float* bh0  = (const float*)d_in[10];
  const float* Wi1  = (const float*)d_in[11];
  const float* Wh1  = (const float*)d_in[12];
  const float* bi1  = (const float*)d_in[13];
  const float* bh1  = (const float*)d_in[14];
  const float* W2   = (const float*)d_in[15];
  const float* b2   = (const float*)d_in[16];
  const float* W3   = (const float*)d_in[17];
  const float* b3   = (const float*)d_in[18];
  float* out = (float*)d_out;
  float* ws  = (float*)d_ws;

  const size_t WBASE = 152576;
  const size_t NEED = WBASE +
      ((size_t)4 * G3 * KP + (size_t)408 * KP + (size_t)65536) * 2;

  void* args[] = { &y, &m1x0, &F, &Hm, &h0, &W1, &b1, &Wi0, &Wh0, &bi0, &bh0,
                   &Wi1, &Wh1, &bi1, &bh1, &W2, &b2, &W3, &b3, &out, &ws };

  if (ws_size >= NEED) {
    // zero all flags: arrival(256) + release(1) + vflag(17) + aflag(1) + kinpack
    hipMemsetAsync((char*)d_ws + 33728 * sizeof(float), 0, 276 * 64, stream);
    _Float16* wh = (_Float16*)((char*)d_ws + WBASE);
    convh<<<2048, 256, 0, stream>>>(Wi0, wh,                         G3, H1,  G3);
    convh<<<2048, 256, 0, stream>>>(Wh0, wh + (size_t)G3 * KP,       G3, HID, G3);
    convh<<<2048, 256, 0, stream>>>(Wi1, wh + (size_t)2 * G3 * KP,   G3, HID, G3);
    convh<<<2048, 256, 0, stream>>>(Wh1, wh + (size_t)3 * G3 * KP,   G3, HID, G3);
    convh<<<2048, 256, 0, stream>>>(W2,  wh + (size_t)4 * G3 * KP,   H2, HID, 408);
    convw1<<<256, 256, 0, stream>>>(W1,  wh + (size_t)4 * G3 * KP + (size_t)408 * KP);
    hipLaunchCooperativeKernel((const void*)knet_f16, dim3(NB), dim3(NT),
                               args, 0, stream);
  } else {
    hipMemsetAsync((char*)d_ws + 26624 * sizeof(float), 0, NB * 64 + 64, stream);
    hipLaunchCooperativeKernel((const void*)knet_f32, dim3(NB), dim3(NT),
                               args, 0, stream);
  }
}